// Round 4
// baseline (303.694 us; speedup 1.0000x reference)
//
#include <hip/hip_runtime.h>
#include <math.h>

#define GELU(v) (0.5f * (v) * (1.0f + erff((v)*0.70710678118654752440f)))

// ---------------- Setup: fold/transpose weights --------------------------------
// fwe2[grp(4)][ic(16)][k(9)][o(8)]            : enc2 transposed    (4608)
// fwd1[grp(2)][ic(32)][phase(4)][tap(4)][o(8)]: dec1 up2-folded    (8192)
// fwd2[ic(16)][phase(4)][tap(4)]              : dec2 up2-folded    (256)
__global__ __launch_bounds__(256) void k_fold(const float* __restrict__ e2w,
                                              const float* __restrict__ d1w,
                                              const float* __restrict__ d2w,
                                              float* __restrict__ fwe2,
                                              float* __restrict__ fwd1,
                                              float* __restrict__ fwd2) {
  int i = blockIdx.x * 256 + threadIdx.x;
  if (i < 4608) {
    int o = i & 7, k = (i >> 3) % 9, ic = (i / 72) & 15, grp = i / 1152;
    fwe2[i] = e2w[((grp * 8 + o) * 16 + ic) * 9 + k];
  } else if (i < 12800) {
    int j = i - 4608;
    int o = j & 7, pt = (j >> 3) & 15, ic = (j >> 7) & 31, grp = j >> 12;
    int a = pt >> 3, b2 = (pt >> 2) & 1, dy = (pt >> 1) & 1, dx = pt & 1;
    const float* wsrc = d1w + ((grp * 8 + o) * 32 + ic) * 9;
    float s = 0.f;
    for (int ky = 0; ky < 3; ++ky) {
      int rm = (a == 0) ? (ky == 0 ? 0 : 1) : (ky == 2 ? 1 : 0);
      if (rm != dy) continue;
      for (int kx = 0; kx < 3; ++kx) {
        int cm = (b2 == 0) ? (kx == 0 ? 0 : 1) : (kx == 2 ? 1 : 0);
        if (cm == dx) s += wsrc[ky * 3 + kx];
      }
    }
    fwd1[j] = s;
  } else if (i < 13056) {
    int j = i - 12800;
    int pt = j & 15, ic = j >> 4;
    int a = pt >> 3, b2 = (pt >> 2) & 1, dy = (pt >> 1) & 1, dx = pt & 1;
    const float* wsrc = d2w + ic * 9;
    float s = 0.f;
    for (int ky = 0; ky < 3; ++ky) {
      int rm = (a == 0) ? (ky == 0 ? 0 : 1) : (ky == 2 ? 1 : 0);
      if (rm != dy) continue;
      for (int kx = 0; kx < 3; ++kx) {
        int cm = (b2 == 0) ? (kx == 0 ? 0 : 1) : (kx == 2 ? 1 : 0);
        if (cm == dx) s += wsrc[ky * 3 + kx];
      }
    }
    fwd2[j] = s;
  }
}

// ---------------- Kernel A: conv1 (1->16) + maxpool2 + gelu --------------------
__global__ __launch_bounds__(256) void k_enc1(const float* __restrict__ x,
                                              const float* __restrict__ w,
                                              const float* __restrict__ bias,
                                              float* __restrict__ h1) {
  int gid = blockIdx.x * 256 + threadIdx.x;
  int xx = gid & 127, yy = (gid >> 7) & 127, b = gid >> 14;
  const float* xp = x + (size_t)b * 65536;
  int r0 = 2 * yy - 1, c0 = 2 * xx - 1;
  float in[4][4];
#pragma unroll
  for (int i = 0; i < 4; ++i) {
    int r = r0 + i;
    bool rv = (unsigned)r < 256u;
#pragma unroll
    for (int j = 0; j < 4; ++j) {
      int c = c0 + j;
      in[i][j] = (rv && (unsigned)c < 256u) ? xp[r * 256 + c] : 0.0f;
    }
  }
  float* op = h1 + (size_t)b * 262144 + yy * 128 + xx;
#pragma unroll
  for (int oc = 0; oc < 16; ++oc) {
    const float* wp = w + oc * 9;  // uniform -> s_load
    float s00 = 0.f, s01 = 0.f, s10 = 0.f, s11 = 0.f;
#pragma unroll
    for (int ky = 0; ky < 3; ++ky)
#pragma unroll
      for (int kx = 0; kx < 3; ++kx) {
        float wv = wp[ky * 3 + kx];
        s00 = fmaf(in[ky][kx], wv, s00);
        s01 = fmaf(in[ky][kx + 1], wv, s01);
        s10 = fmaf(in[ky + 1][kx], wv, s10);
        s11 = fmaf(in[ky + 1][kx + 1], wv, s11);
      }
    float m = fmaxf(fmaxf(s00, s01), fmaxf(s10, s11)) + bias[oc];
    op[oc * 16384] = GELU(m);
  }
}

// ---------------- Kernel B: conv2 (16->32) + maxpool2 --------------------------
__global__ __launch_bounds__(256) void k_enc2(const float* __restrict__ h1,
                                              const float* __restrict__ fwe2,
                                              const float* __restrict__ bias,
                                              float* __restrict__ h2) {
  __shared__ float st[16 * 360];  // [ic][18 rows][20: evens 0-9, odds 10-19]
  int tid = threadIdx.x;
  int b = blockIdx.y;
  int Y0 = (blockIdx.x >> 3) * 8, X0 = (blockIdx.x & 7) * 8;
  int r_s = 2 * Y0 - 1, c_s = 2 * X0 - 1;
  const float* ip = h1 + (size_t)b * 262144;
  for (int i = tid; i < 5184; i += 256) {  // 16 ic x 18 x 18
    int ic = i / 324, rr = (i % 324) / 18, cc = i % 18;
    int r = r_s + rr, c = c_s + cc;
    float v = ((unsigned)r < 128u && (unsigned)c < 128u) ? ip[ic * 16384 + r * 128 + c] : 0.f;
    st[ic * 360 + rr * 20 + (cc & 1) * 10 + (cc >> 1)] = v;
  }
  __syncthreads();
  int lane = tid & 63;
  int grp = __builtin_amdgcn_readfirstlane(tid >> 6);
  int oc0 = grp * 8;
  int ty = lane >> 3, tx = lane & 7;
  float acc[4][8];
#pragma unroll
  for (int p = 0; p < 4; ++p)
#pragma unroll
    for (int o = 0; o < 8; ++o) acc[p][o] = 0.f;
  const float* wgrp = fwe2 + grp * 1152;  // scalar base
#pragma unroll 1
  for (int ic = 0; ic < 16; ++ic) {
    const float* t = st + ic * 360 + (2 * ty) * 20 + tx;
    float iv[4][4];
#pragma unroll
    for (int dy = 0; dy < 4; ++dy)
#pragma unroll
      for (int dx = 0; dx < 4; ++dx)
        iv[dy][dx] = t[dy * 20 + (dx & 1) * 10 + (dx >> 1)];
    const float* wp = wgrp + ic * 72;  // scalar loads
#pragma unroll
    for (int k = 0; k < 9; ++k) {
      int ky = k / 3, kx = k % 3;
#pragma unroll
      for (int o = 0; o < 8; ++o) {
        float wv = wp[k * 8 + o];
        acc[0][o] = fmaf(iv[ky][kx], wv, acc[0][o]);
        acc[1][o] = fmaf(iv[ky][kx + 1], wv, acc[1][o]);
        acc[2][o] = fmaf(iv[ky + 1][kx], wv, acc[2][o]);
        acc[3][o] = fmaf(iv[ky + 1][kx + 1], wv, acc[3][o]);
      }
    }
  }
  float* op = h2 + (size_t)b * 131072 + (Y0 + ty) * 64 + X0 + tx;
#pragma unroll
  for (int o = 0; o < 8; ++o) {
    float m = fmaxf(fmaxf(acc[0][o], acc[1][o]), fmaxf(acc[2][o], acc[3][o])) + bias[oc0 + o];
    op[(oc0 + o) * 4096] = m;
  }
}

// ---------------- Kernel C1: VQ distance scan, 4 tokens/thread -----------------
// 4 chunks x 128 blocks; 128 FMAs per 32-float codebook row load. Chunk-0 blocks
// also emit fsq[t]=||f||^2 so merge never re-reads h2.
__global__ __launch_bounds__(256) void k_vq_chunk(const float* __restrict__ h2,
                                                  const float* __restrict__ cb,
                                                  float* __restrict__ dists,
                                                  int* __restrict__ idxs,
                                                  float* __restrict__ fsq) {
  __shared__ float scsq[128];
  int tid = threadIdx.x;
  int chunk = blockIdx.x >> 7;        // 0..3
  int jbase = chunk << 7;
  if (tid < 128) {
    const float* row = cb + (size_t)(jbase + tid) * 32;
    float s = 0.f;
#pragma unroll
    for (int d = 0; d < 32; ++d) s = fmaf(row[d], row[d], s);
    scsq[tid] = s;
  }
  __syncthreads();
  int base = (blockIdx.x & 127) * 256 + tid;  // 0..32767
  float f[4][32];
  float fs[4];
  size_t a[4];
#pragma unroll
  for (int k = 0; k < 4; ++k) {
    int t = base + k * 32768;
    a[k] = (size_t)(t >> 12) * 131072 + (t & 4095);
    float s = 0.f;
#pragma unroll
    for (int c = 0; c < 32; ++c) {
      float v = h2[a[k] + c * 4096];
      f[k][c] = v;
      s = fmaf(v, v, s);
    }
    fs[k] = s;
  }
  if (chunk == 0) {
#pragma unroll
    for (int k = 0; k < 4; ++k) fsq[base + k * 32768] = fs[k];
  }
  float best[4] = {3.4e38f, 3.4e38f, 3.4e38f, 3.4e38f};
  int bi[4] = {jbase, jbase, jbase, jbase};
  const float4* r4 = (const float4*)(cb + (size_t)jbase * 32);
#pragma unroll 1
  for (int jl = 0; jl < 128; ++jl) {
    const float4* row = r4 + (jl << 3);
    float da[4] = {0.f, 0.f, 0.f, 0.f}, db[4] = {0.f, 0.f, 0.f, 0.f};
#pragma unroll
    for (int q = 0; q < 8; q += 2) {
      float4 v = row[q], u = row[q + 1];
#pragma unroll
      for (int k = 0; k < 4; ++k) {
        da[k] = fmaf(v.x, f[k][4*q+0], da[k]); da[k] = fmaf(v.y, f[k][4*q+1], da[k]);
        da[k] = fmaf(v.z, f[k][4*q+2], da[k]); da[k] = fmaf(v.w, f[k][4*q+3], da[k]);
        db[k] = fmaf(u.x, f[k][4*q+4], db[k]); db[k] = fmaf(u.y, f[k][4*q+5], db[k]);
        db[k] = fmaf(u.z, f[k][4*q+6], db[k]); db[k] = fmaf(u.w, f[k][4*q+7], db[k]);
      }
    }
    float csq = scsq[jl];
#pragma unroll
    for (int k = 0; k < 4; ++k) {
      float d = csq - 2.0f * (da[k] + db[k]);
      if (d < best[k]) { best[k] = d; bi[k] = jbase + jl; }  // strict <: first-min
    }
  }
  size_t cbase = (size_t)chunk * 131072;
#pragma unroll
  for (int k = 0; k < 4; ++k) {
    dists[cbase + base + k * 32768] = best[k];
    idxs[cbase + base + k * 32768] = bi[k];
  }
}

// ---------------- Kernel C2: merge 4 candidates, write q, idx, loss ------------
// Never reads h2: fully overwrites it with cb[bi]; loss = bd + ||f||^2 (fsq).
__global__ __launch_bounds__(256) void k_vq_merge(float* __restrict__ h2,
                                                  const float* __restrict__ cb,
                                                  const float* __restrict__ dists,
                                                  const int* __restrict__ idxs,
                                                  const float* __restrict__ fsq,
                                                  float* __restrict__ idxout,
                                                  float* __restrict__ lossout) {
  __shared__ float sred[4];
  int tid = threadIdx.x;
  int t = blockIdx.x * 256 + tid;
  float bd = dists[t];
  int bi = idxs[t];
#pragma unroll
  for (int k = 1; k < 4; ++k) {  // ascending chunk order: ties -> lowest idx
    float dk = dists[(size_t)k * 131072 + t];
    int ik = idxs[(size_t)k * 131072 + t];
    if (dk < bd) { bd = dk; bi = ik; }
  }
  size_t a = (size_t)(t >> 12) * 131072 + (t & 4095);
  const float4* q4 = (const float4*)(cb + (size_t)bi * 32);
#pragma unroll
  for (int c8 = 0; c8 < 8; ++c8) {
    float4 v = q4[c8];
    h2[a + (4 * c8 + 0) * 4096] = v.x;
    h2[a + (4 * c8 + 1) * 4096] = v.y;
    h2[a + (4 * c8 + 2) * 4096] = v.z;
    h2[a + (4 * c8 + 3) * 4096] = v.w;
  }
  idxout[t] = (float)bi;
  float loss = bd + fsq[t];  // = ||q - f||^2
#pragma unroll
  for (int off = 32; off > 0; off >>= 1) loss += __shfl_down(loss, off, 64);
  if ((tid & 63) == 0) sred[tid >> 6] = loss;
  __syncthreads();
  if (tid == 0)
    atomicAdd(lossout, ((sred[0] + sred[1]) + (sred[2] + sred[3])) * (1.0f / 4194304.0f));
}

// ---------------- Kernel D: up2 + conv (32->16) + gelu, phase-folded -----------
__global__ __launch_bounds__(256) void k_dec1(const float* __restrict__ q,
                                              const float* __restrict__ fwd1,
                                              const float* __restrict__ bias,
                                              float* __restrict__ o) {
  __shared__ float st[32 * 200];  // [ic][10 rows][20]
  int tid = threadIdx.x;
  int b = blockIdx.y;
  int R0 = (blockIdx.x >> 2) * 8, C0 = (blockIdx.x & 3) * 16;
  const float* ip = q + (size_t)b * 131072;
  for (int i = tid; i < 5760; i += 256) {  // 32 ic x 10 x 18
    int ic = i / 180, rr = (i % 180) / 18, cc = i % 18;
    int r = R0 - 1 + rr, c = C0 - 1 + cc;
    st[ic * 200 + rr * 20 + cc] =
        ((unsigned)r < 64u && (unsigned)c < 64u) ? ip[ic * 4096 + r * 64 + c] : 0.f;
  }
  __syncthreads();
  int lane = tid & 63, wid = tid >> 6;
  int qx = wid & 1;
  int grp = __builtin_amdgcn_readfirstlane(wid >> 1);
  int ty = lane >> 3, tx = qx * 8 + (lane & 7);
  float acc[4][8];
#pragma unroll
  for (int p = 0; p < 4; ++p)
#pragma unroll
    for (int o2 = 0; o2 < 8; ++o2) acc[p][o2] = 0.f;
  const float* wb = fwd1 + grp * 4096;
#pragma unroll 1
  for (int ic = 0; ic < 32; ++ic) {
    const float* t = st + ic * 200 + ty * 20 + tx;
    float i3[3][3];
#pragma unroll
    for (int dy = 0; dy < 3; ++dy)
#pragma unroll
      for (int dx = 0; dx < 3; ++dx) i3[dy][dx] = t[dy * 20 + dx];
    const float* wp = wb + ic * 128;  // scalar loads
#pragma unroll
    for (int p = 0; p < 4; ++p) {
      int a = p >> 1, b2 = p & 1;
#pragma unroll
      for (int tp = 0; tp < 4; ++tp) {
        int dy = tp >> 1, dx = tp & 1;
        float iv = i3[a + dy][b2 + dx];
#pragma unroll
        for (int o2 = 0; o2 < 8; ++o2)
          acc[p][o2] = fmaf(iv, wp[(p * 4 + tp) * 8 + o2], acc[p][o2]);
      }
    }
  }
  int Y = 2 * (R0 + ty), X = 2 * (C0 + tx);
#pragma unroll
  for (int o2 = 0; o2 < 8; ++o2) {
    int oc = grp * 8 + o2;
    float bb = bias[oc];
    float* p = o + (size_t)b * 262144 + (size_t)oc * 16384 + Y * 128 + X;
    float2 r0v, r1v;
    r0v.x = GELU(acc[0][o2] + bb);
    r0v.y = GELU(acc[1][o2] + bb);
    r1v.x = GELU(acc[2][o2] + bb);
    r1v.y = GELU(acc[3][o2] + bb);
    *(float2*)p = r0v;
    *(float2*)(p + 128) = r1v;
  }
}

// ---------------- Kernel E: up2 + conv (16->1) + clip, phase-folded ------------
__global__ __launch_bounds__(256) void k_dec2(const float* __restrict__ d1,
                                              const float* __restrict__ fwd2,
                                              const float* __restrict__ bias,
                                              float* __restrict__ out) {
  __shared__ float st[16 * 360];  // [ic][18 rows][20]
  int tid = threadIdx.x;
  int b = blockIdx.y;
  int R0 = (blockIdx.x >> 3) * 16, C0 = (blockIdx.x & 7) * 16;
  const float* ip = d1 + (size_t)b * 262144;
  for (int i = tid; i < 5184; i += 256) {  // 16 ic x 18 x 18
    int ic = i / 324, rr = (i % 324) / 18, cc = i % 18;
    int r = R0 - 1 + rr, c = C0 - 1 + cc;
    st[ic * 360 + rr * 20 + cc] =
        ((unsigned)r < 128u && (unsigned)c < 128u) ? ip[ic * 16384 + r * 128 + c] : 0.f;
  }
  __syncthreads();
  int lane = tid & 63, wid = tid >> 6;
  int qy = wid >> 1, qx = wid & 1;
  int ty = qy * 8 + (lane >> 3), tx = qx * 8 + (lane & 7);
  float acc[4] = {0.f, 0.f, 0.f, 0.f};
#pragma unroll 1
  for (int ic = 0; ic < 16; ++ic) {
    const float* t = st + ic * 360 + ty * 20 + tx;
    float i3[3][3];
#pragma unroll
    for (int dy = 0; dy < 3; ++dy)
#pragma unroll
      for (int dx = 0; dx < 3; ++dx) i3[dy][dx] = t[dy * 20 + dx];
    const float* wp = fwd2 + ic * 16;  // scalar loads
#pragma unroll
    for (int p = 0; p < 4; ++p) {
      int a = p >> 1, b2 = p & 1;
#pragma unroll
      for (int tp = 0; tp < 4; ++tp) {
        int dy = tp >> 1, dx = tp & 1;
        acc[p] = fmaf(i3[a + dy][b2 + dx], wp[p * 4 + tp], acc[p]);
      }
    }
  }
  float bv = bias[0];
  int Y = 2 * (R0 + ty), X = 2 * (C0 + tx);
  float* op = out + (size_t)b * 65536 + Y * 256 + X;
  float2 r0v, r1v;
  r0v.x = fminf(1.0f, fmaxf(-1.0f, acc[0] + bv));
  r0v.y = fminf(1.0f, fmaxf(-1.0f, acc[1] + bv));
  r1v.x = fminf(1.0f, fmaxf(-1.0f, acc[2] + bv));
  r1v.y = fminf(1.0f, fmaxf(-1.0f, acc[3] + bv));
  *(float2*)op = r0v;
  *(float2*)(op + 256) = r1v;
}

extern "C" void kernel_launch(void* const* d_in, const int* in_sizes, int n_in,
                              void* d_out, int out_size, void* d_ws, size_t ws_size,
                              hipStream_t stream) {
  const float* x   = (const float*)d_in[0];
  const float* e1w = (const float*)d_in[1];
  const float* e1b = (const float*)d_in[2];
  const float* e2w = (const float*)d_in[3];
  const float* e2b = (const float*)d_in[4];
  const float* cb  = (const float*)d_in[5];
  const float* d1w = (const float*)d_in[6];
  const float* d1b = (const float*)d_in[7];
  const float* d2w = (const float*)d_in[8];
  const float* d2b = (const float*)d_in[9];

  float* out = (float*)d_out;
  float* y       = out;                       // [32,1,256,256] = 2097152
  float* idxout  = out + 2097152;             // [32,64,64]     = 131072 (as float)
  float* lossout = out + 2097152 + 131072;    // scalar

  float* ws = (float*)d_ws;
  float* h1      = ws;                        // [32,16,128,128] = 8388608 floats
  float* h2      = ws + 8388608;              // [32,32,64,64]   = 4194304 floats
  float* fwe2    = ws + 12582912;             // 4608
  float* fwd1    = ws + 12587520;             // 8192
  float* fwd2    = ws + 12595712;             // 256
  // VQ intermediates reuse the (dead-after-enc2) h1 region; consumed by merge
  // BEFORE dec1 writes d1o over the same region (kernels serialize on stream):
  float* dists   = ws;                        // 4 x 131072 floats
  int*   idxs    = (int*)(ws + 524288);       // 4 x 131072 ints
  float* fsq     = ws + 1048576;              // 131072 floats
  float* d1o     = h1;                        // dec1 output reuses h1

  k_fold<<<dim3(51), 256, 0, stream>>>(e2w, d1w, d2w, fwe2, fwd1, fwd2);
  k_enc1<<<dim3(2048), 256, 0, stream>>>(x, e1w, e1b, h1);
  k_enc2<<<dim3(64, 32), 256, 0, stream>>>(h1, fwe2, e2b, h2);
  k_vq_chunk<<<dim3(512), 256, 0, stream>>>(h2, cb, dists, idxs, fsq);
  hipMemsetAsync(lossout, 0, sizeof(float), stream);
  k_vq_merge<<<dim3(512), 256, 0, stream>>>(h2, cb, dists, idxs, fsq, idxout, lossout);
  k_dec1<<<dim3(32, 32), 256, 0, stream>>>(h2, fwd1, d1b, d1o);
  k_dec2<<<dim3(64, 32), 256, 0, stream>>>(d1o, fwd2, d2b, y);
}